// Round 9
// baseline (144.185 us; speedup 1.0000x reference)
//
#include <hip/hip_runtime.h>
#include <hip/hip_bf16.h>

// ---------------------------------------------------------------------------
// Sizes (fixed)
// ---------------------------------------------------------------------------
#define BATCH 4
#define NN    256
#define DD    600
#define HH    256
#define MROWS (BATCH*NN)   // 1024
#define KPAD  640          // DD padded to multiple of 64

typedef __attribute__((ext_vector_type(8))) short bf16x8;   // 8 bf16 (4 VGPRs)
typedef __attribute__((ext_vector_type(4))) float f32x4;

__device__ __forceinline__ void gload16(const void* g, void* l)
{
    __builtin_amdgcn_global_load_lds(
        (const __attribute__((address_space(1))) void*)g,
        (__attribute__((address_space(3))) void*)l, 16, 0, 0);
}

__device__ __forceinline__ void waitcnt_vm(int n)
{
    switch (n) {
    case 0:  asm volatile("s_waitcnt vmcnt(0)"  ::: "memory"); break;
    case 2:  asm volatile("s_waitcnt vmcnt(2)"  ::: "memory"); break;
    case 4:  asm volatile("s_waitcnt vmcnt(4)"  ::: "memory"); break;
    case 6:  asm volatile("s_waitcnt vmcnt(6)"  ::: "memory"); break;
    case 8:  asm volatile("s_waitcnt vmcnt(8)"  ::: "memory"); break;
    default: asm volatile("s_waitcnt vmcnt(0)"  ::: "memory"); break;
    }
}

__device__ __forceinline__ void lgkm0_barrier()
{
    asm volatile("s_waitcnt lgkmcnt(0)" ::: "memory");
    __builtin_amdgcn_s_barrier();
}

// XCD-chunked bijective remap (m204) of flattened block id
__device__ __forceinline__ int xcd_remap(int lin, int nwg)
{
    const int q = nwg >> 3, r = nwg & 7;
    const int xcd = lin & 7, off = lin >> 3;
    return (xcd < r ? xcd * (q + 1) : r * (q + 1) + (xcd - r) * q) + off;
}

// ---------------------------------------------------------------------------
// gemm_cvt: C = A[1024,K] @ B^T implied (+bias cols<biasN), K = NK*64.
// B given as RAW fp32 K-major source (W [600][600] or packed aW1 [1200][256]);
// each block converts+transposes its own B tiles into LDS (reg-staged bf16
// scatter-writes, rotated order; XOR-swizzled to match ds_read_b128 path).
// A: AF32 -> raw fp32 (reg-staged cvt, hGEMM0); else bf16 via gload_lds ring-4.
// Tile 64x64x64, 4 waves. WF32/WB16/WHT as before. No batch (z==1).
// ---------------------------------------------------------------------------
template<bool AF32, bool RELU, bool WF32, bool WB16, bool WHT, bool BPACK, int NK>
__global__ __launch_bounds__(256) void gemm_cvt(
    const void* __restrict__ Asrc, const float* __restrict__ Bsrc,
    const float* __restrict__ bias,
    float* __restrict__ Cf, __hip_bfloat16* __restrict__ Cb,
    __hip_bfloat16* __restrict__ hT,
    int lda, int ldcf, int ldcb, int Nvalid, int biasN)
{
    __shared__ __align__(16) char lds[49152];   // A: [0,32K) ring/dbuf ; B: [32K,48K) dbuf

    const int nwg = gridDim.x * gridDim.y;
    int lin = xcd_remap(blockIdx.x + gridDim.x * blockIdx.y, nwg);
    const int bx = lin % gridDim.x;
    const int by = lin / gridDim.x;

    const int tid  = threadIdx.x;
    const int lane = tid & 63;
    const int wid  = tid >> 6;
    const int wr   = wid >> 1;
    const int wc   = wid & 1;
    const int row0 = by * 64;
    const int col0 = bx * 64;

    // ---------------- B staging (fp32 -> bf16 transpose into LDS) ----------
    const int bkk = tid >> 4;          // k_rel base (0..15), +16p
    const int bn4 = (tid & 15) * 4;    // n within tile
    const int bpr = (BPACK && col0 >= 256) ? 1 : 0;   // block-uniform
    float4 rB[4];

    auto loadB = [&](int t) {
        const int k0 = t * 64;
        #pragma unroll
        for (int p = 0; p < 4; ++p) {
            const int gk = k0 + bkk + 16 * p;
            const int gn = col0 + bn4;
            bool v;
            const float* src;
            if (BPACK) {
                src = Bsrc + ((long long)(gk + 600 * bpr)) * 256 + (gn - 256 * bpr);
                v = gk < 600;
            } else {
                src = Bsrc + (long long)gk * 600 + gn;
                v = (gk < 600) && (gn < 600);
            }
            rB[p] = v ? *(const float4*)src : make_float4(0.f, 0.f, 0.f, 0.f);
        }
    };
    auto writeB = [&](int t) {
        char* dB = lds + 32768 + (t & 1) * 8192;
        const int rot = tid & 15;
        #pragma unroll
        for (int i = 0; i < 16; ++i) {
            const int e = (i + rot) & 15;
            const int p = e >> 2, j = e & 3;
            const int n = bn4 + j;
            const int k = bkk + 16 * p;
            const float* f = (const float*)&rB[p];
            *(__hip_bfloat16*)(dB + n * 128 + ((2 * k) ^ ((n & 7) << 4))) =
                __float2bfloat16(f[j]);
        }
    };

    // ---------------- A staging ----------
    // AF32 path: raw fp32 reg-staged cvt (dbuf)
    const int am16 = tid >> 4;         // row base, +16p
    const int ak4  = (tid & 15) * 4;   // k within tile
    float4 rA[4];
    auto loadA32 = [&](int t) {
        const int k0 = t * 64;
        #pragma unroll
        for (int p = 0; p < 4; ++p) {
            const int m  = row0 + am16 + 16 * p;
            const int gk = k0 + ak4;
            rA[p] = (gk < 600)
                ? *(const float4*)((const float*)Asrc + (long long)m * lda + gk)
                : make_float4(0.f, 0.f, 0.f, 0.f);
        }
    };
    auto writeA32 = [&](int t) {
        char* dA = lds + (t & 1) * 8192;
        #pragma unroll
        for (int p = 0; p < 4; ++p) {
            const int m = am16 + 16 * p;
            __align__(8) __hip_bfloat16 o[4] = {
                __float2bfloat16(rA[p].x), __float2bfloat16(rA[p].y),
                __float2bfloat16(rA[p].z), __float2bfloat16(rA[p].w)};
            *(float2*)(dA + m * 128 + ((2 * ak4) ^ ((m & 7) << 4))) = *(float2*)o;
        }
    };
    // bf16 path: gload_lds ring-4, pre-swizzled source (as R6/R8)
    const int sr   = tid >> 3;
    const int scb  = (tid & 7) * 16;
    const int scbs = scb ^ ((sr & 7) << 4);
    const char* Ab  = (const char*)Asrc + (long long)row0 * lda * 2;
    const char* gA0 = Ab + (long long)sr        * (lda * 2) + scbs;
    const char* gA1 = Ab + (long long)(sr + 32) * (lda * 2) + scbs;
    auto issueA = [&](int t) {
        char* bA = lds + (t & 3) * 8192;
        const long long off = (long long)t * 128;
        gload16(gA0 + off, bA + wid * 1024);
        gload16(gA1 + off, bA + 4096 + wid * 1024);
    };

    // ---------------- compute ----------
    f32x4 acc[2][2] = {};
    const int fr = lane & 15;
    const int kg = (lane >> 4) * 16;
    const int xv = (fr & 7) << 4;

    auto compute = [&](int t) {
        const char* lA = lds + (AF32 ? (t & 1) : (t & 3)) * 8192;
        const char* lB = lds + 32768 + (t & 1) * 8192;
        #pragma unroll
        for (int ks = 0; ks < 2; ++ks) {
            const int kb = ks * 64 + kg;
            bf16x8 a0 = *(const bf16x8*)(lA + (wr * 32 + fr)      * 128 + (kb ^ xv));
            bf16x8 a1 = *(const bf16x8*)(lA + (wr * 32 + 16 + fr) * 128 + (kb ^ xv));
            bf16x8 b0 = *(const bf16x8*)(lB + (wc * 32 + fr)      * 128 + (kb ^ xv));
            bf16x8 b1 = *(const bf16x8*)(lB + (wc * 32 + 16 + fr) * 128 + (kb ^ xv));
            acc[0][0] = __builtin_amdgcn_mfma_f32_16x16x32_bf16(a0, b0, acc[0][0], 0, 0, 0);
            acc[0][1] = __builtin_amdgcn_mfma_f32_16x16x32_bf16(a0, b1, acc[0][1], 0, 0, 0);
            acc[1][0] = __builtin_amdgcn_mfma_f32_16x16x32_bf16(a1, b0, acc[1][0], 0, 0, 0);
            acc[1][1] = __builtin_amdgcn_mfma_f32_16x16x32_bf16(a1, b1, acc[1][1], 0, 0, 0);
        }
    };

    // ---------------- pipeline ----------
    if constexpr (AF32) {
        loadA32(0); loadB(0);
        waitcnt_vm(0);
        writeA32(0); writeB(0);
        lgkm0_barrier();
        #pragma unroll
        for (int t = 0; t < NK; ++t) {
            if (t + 1 < NK) { loadA32(t + 1); loadB(t + 1); }
            compute(t);
            if (t + 1 < NK) { waitcnt_vm(0); writeA32(t + 1); writeB(t + 1); }
            lgkm0_barrier();
        }
    } else {
        loadB(0);
        issueA(0); issueA(1); issueA(2);
        waitcnt_vm(4);                    // B(0) + A(0) drained, A(1..2) in flight
        writeB(0);
        lgkm0_barrier();
        #pragma unroll
        for (int t = 0; t < NK; ++t) {
            if (t + 1 < NK) loadB(t + 1);
            if (t + 3 < NK) issueA(t + 3);
            compute(t);
            if (t + 1 < NK) {
                waitcnt_vm((t <= NK - 4) ? 2 : 0);   // B(t+1)+A(t+1) drained
                writeB(t + 1);
            }
            lgkm0_barrier();
        }
    }
    __syncthreads();

    // ---------------- epilogue ----------
    const int er = (lane >> 4) * 4;
    const int ec = lane & 15;
    __hip_bfloat16* sT = (__hip_bfloat16*)lds;   // [64][72] retile buffer

    #pragma unroll
    for (int mi = 0; mi < 2; ++mi) {
        #pragma unroll
        for (int ni = 0; ni < 2; ++ni) {
            const int lr0 = wr * 32 + mi * 16 + er;
            const int lc  = wc * 32 + ni * 16 + ec;
            const int gr = row0 + lr0;
            const int gc = col0 + lc;
            const float bv = (bias != nullptr && gc < biasN) ? bias[gc] : 0.f;
            #pragma unroll
            for (int r = 0; r < 4; ++r) {
                float v = acc[mi][ni][r] + bv;
                if (RELU) v = fmaxf(v, 0.f);
                const __hip_bfloat16 hv = __float2bfloat16(v);
                const long long row = gr + r;
                if (WF32 && gc < Nvalid)
                    Cf[row * ldcf + gc] = v;
                if (WB16)
                    Cb[row * ldcb + gc] = hv;
                if (WHT)
                    sT[(lr0 + r) * 72 + lc] = hv;
            }
        }
    }

    if (WHT) {
        __syncthreads();
        const int b  = row0 >> 8;
        const int i0 = row0 & 255;
        const int cc = tid >> 3;
        const int ch = tid & 7;
        #pragma unroll
        for (int p = 0; p < 2; ++p) {
            const int d = col0 + cc + p * 32;
            __align__(16) __hip_bfloat16 tmp[8];
            #pragma unroll
            for (int u = 0; u < 8; ++u)
                tmp[u] = sT[(ch * 8 + u) * 72 + cc + p * 32];
            *(float4*)&hT[((long long)b * KPAD + d) * NN + i0 + ch * 8] = *(float4*)tmp;
        }
    }
}

// ---------------------------------------------------------------------------
// bf16/bf16 MFMA GEMM (out-GEMMs): unchanged from R8 (ring-4 gload_lds).
// ---------------------------------------------------------------------------
template<bool RELU, bool WF32, bool WB16, int NK>
__global__ __launch_bounds__(256) void gemm_mfma(
    const __hip_bfloat16* __restrict__ A, const __hip_bfloat16* __restrict__ BT,
    float* __restrict__ Cf, __hip_bfloat16* __restrict__ Cb,
    int lda, int ldb, int ldcf, int ldcb, int Nvalid,
    long long sA, long long sBT, long long sCf, long long sCb)
{
    __shared__ __align__(16) char lds[65536];

    const int nwg = gridDim.x * gridDim.y * gridDim.z;
    int lin = xcd_remap(blockIdx.x + gridDim.x * (blockIdx.y + gridDim.y * blockIdx.z), nwg);
    const int bx = lin % gridDim.x;
    const int by = (lin / gridDim.x) % gridDim.y;
    const int bz = lin / (gridDim.x * gridDim.y);

    const int tid  = threadIdx.x;
    const int lane = tid & 63;
    const int wid  = tid >> 6;
    const int wr   = wid >> 1;
    const int wc   = wid & 1;
    const int row0 = by * 64;
    const int col0 = bx * 64;

    const char* Ab = (const char*)A + (bz * sA + (long long)row0 * lda) * 2;
    const char* Bb = (const char*)BT + (bz * sBT + (long long)col0 * ldb) * 2;

    const int sr   = tid >> 3;
    const int scb  = (tid & 7) * 16;
    const int scbs = scb ^ ((sr & 7) << 4);

    const char* gA0 = Ab + (long long)sr        * (lda * 2) + scbs;
    const char* gA1 = Ab + (long long)(sr + 32) * (lda * 2) + scbs;
    const char* gB0 = Bb + (long long)sr        * (ldb * 2) + scbs;
    const char* gB1 = Bb + (long long)(sr + 32) * (ldb * 2) + scbs;

    f32x4 acc[2][2] = {};
    const int fr = lane & 15;
    const int kg = (lane >> 4) * 16;
    const int xv = (fr & 7) << 4;

    auto issue = [&](int t) {
        char* bA = lds + (t & 3) * 8192;
        char* bB = lds + 32768 + (t & 3) * 8192;
        const long long off = (long long)t * 128;
        gload16(gA0 + off, bA + wid * 1024);
        gload16(gA1 + off, bA + 4096 + wid * 1024);
        gload16(gB0 + off, bB + wid * 1024);
        gload16(gB1 + off, bB + 4096 + wid * 1024);
    };

    constexpr int PRE = (NK < 3) ? NK : 3;
    #pragma unroll
    for (int p = 0; p < PRE; ++p) issue(p);

    #pragma unroll
    for (int t = 0; t < NK; ++t) {
        const int imax = (t + 2 < NK - 1) ? t + 2 : NK - 1;
        waitcnt_vm(4 * (imax - t));
        __builtin_amdgcn_s_barrier();
        const char* lA = lds + (t & 3) * 8192;
        const char* lB = lds + 32768 + (t & 3) * 8192;
        #pragma unroll
        for (int ks = 0; ks < 2; ++ks) {
            const int kb = ks * 64 + kg;
            bf16x8 a0 = *(const bf16x8*)(lA + (wr * 32 + fr)      * 128 + (kb ^ xv));
            bf16x8 a1 = *(const bf16x8*)(lA + (wr * 32 + 16 + fr) * 128 + (kb ^ xv));
            bf16x8 b0 = *(const bf16x8*)(lB + (wc * 32 + fr)      * 128 + (kb ^ xv));
            bf16x8 b1 = *(const bf16x8*)(lB + (wc * 32 + 16 + fr) * 128 + (kb ^ xv));
            acc[0][0] = __builtin_amdgcn_mfma_f32_16x16x32_bf16(a0, b0, acc[0][0], 0, 0, 0);
            acc[0][1] = __builtin_amdgcn_mfma_f32_16x16x32_bf16(a0, b1, acc[0][1], 0, 0, 0);
            acc[1][0] = __builtin_amdgcn_mfma_f32_16x16x32_bf16(a1, b0, acc[1][0], 0, 0, 0);
            acc[1][1] = __builtin_amdgcn_mfma_f32_16x16x32_bf16(a1, b1, acc[1][1], 0, 0, 0);
        }
        if (t + 3 < NK) issue(t + 3);
    }
    __syncthreads();

    const int er = (lane >> 4) * 4;
    const int ec = lane & 15;
    #pragma unroll
    for (int mi = 0; mi < 2; ++mi) {
        #pragma unroll
        for (int ni = 0; ni < 2; ++ni) {
            const int gr = row0 + wr * 32 + mi * 16 + er;
            const int gc = col0 + wc * 32 + ni * 16 + ec;
            #pragma unroll
            for (int r = 0; r < 4; ++r) {
                float v = acc[mi][ni][r];
                if (RELU) v = fmaxf(v, 0.f);
                const long long row = gr + r;
                if (WF32 && gc < Nvalid)
                    Cf[bz * sCf + row * ldcf + gc] = v;
                if (WB16)
                    Cb[bz * sCb + row * ldcb + gc] = __float2bfloat16(v);
            }
        }
    }
}

// ---------------------------------------------------------------------------
// Attention (unchanged from R8)
// ---------------------------------------------------------------------------
__device__ __forceinline__ void block_max4(float* v, float (*red)[4])
{
    #pragma unroll
    for (int o = 32; o > 0; o >>= 1)
        #pragma unroll
        for (int q = 0; q < 4; ++q) v[q] = fmaxf(v[q], __shfl_down(v[q], o));
    const int lane = threadIdx.x & 63, w = threadIdx.x >> 6;
    if (lane == 0) { red[w][0]=v[0]; red[w][1]=v[1]; red[w][2]=v[2]; red[w][3]=v[3]; }
    __syncthreads();
    #pragma unroll
    for (int q = 0; q < 4; ++q)
        v[q] = fmaxf(fmaxf(red[0][q], red[1][q]), fmaxf(red[2][q], red[3][q]));
    __syncthreads();
}

__device__ __forceinline__ void block_sum4(float* v, float (*red)[4])
{
    #pragma unroll
    for (int o = 32; o > 0; o >>= 1)
        #pragma unroll
        for (int q = 0; q < 4; ++q) v[q] += __shfl_down(v[q], o);
    const int lane = threadIdx.x & 63, w = threadIdx.x >> 6;
    if (lane == 0) { red[w][0]=v[0]; red[w][1]=v[1]; red[w][2]=v[2]; red[w][3]=v[3]; }
    __syncthreads();
    #pragma unroll
    for (int q = 0; q < 4; ++q)
        v[q] = red[0][q] + red[1][q] + red[2][q] + red[3][q];
    __syncthreads();
}

__global__ __launch_bounds__(256) void attn_kernel(
    const float* __restrict__ LR, const float* __restrict__ aW2,
    const float* __restrict__ ab2, const float* __restrict__ adj,
    __hip_bfloat16* __restrict__ att)
{
    __shared__ float sL[4][HH];
    __shared__ float sW[HH];
    __shared__ float red[4][4];

    const int b  = blockIdx.y;
    const int i0 = blockIdx.x * 4;
    const int j  = threadIdx.x;

    float a[4];
    #pragma unroll
    for (int q = 0; q < 4; ++q)
        a[q] = adj[((long long)(b * NN + i0 + q)) * NN + j];
    const float ab2v = ab2[0];

    sW[j] = aW2[j];
    #pragma unroll
    for (int q = 0; q < 4; ++q)
        sL[q][j] = LR[((long long)(b * NN + i0 + q)) * 512 + j];
    __syncthreads();

    const float* rp = LR + ((long long)(b * NN + j)) * 512 + HH;
    float acc[4] = {0.f, 0.f, 0.f, 0.f};
    for (int h = 0; h < HH; h += 8) {
        const float4 ra = *(const float4*)(rp + h);
        const float4 rb = *(const float4*)(rp + h + 4);
        const float4 w0 = *(const float4*)&sW[h];
        const float4 w1 = *(const float4*)&sW[h + 4];
        #pragma unroll
        for (int q = 0; q < 4; ++q) {
            const float4 l0 = *(const float4*)&sL[q][h];
            const float4 l1 = *(const float4*)&sL[q][h + 4];
            float s = fmaxf(l0.x + ra.x, 0.f) * w0.x;
            s += fmaxf(l0.y + ra.y, 0.f) * w0.y;
            s += fmaxf(l0.z + ra.z, 0.f) * w0.z;
            s += fmaxf(l0.w + ra.w, 0.f) * w0.w;
            s += fmaxf(l1.x + rb.x, 0.f) * w1.x;
            s += fmaxf(l1.y + rb.y, 0.f) * w1.y;
            s += fmaxf(l1.z + rb.z, 0.f) * w1.z;
            s += fmaxf(l1.w + rb.w, 0.f) * w1.w;
            acc[q] += s;
        }
    }

    float m[4];
    #pragma unroll
    for (int q = 0; q < 4; ++q) {
        float e = acc[q] + ab2v;
        e = (e > 0.f) ? e : 0.01f * e;
        m[q] = (a[q] == 0.f) ? -1e9f : e;
    }
    float mx[4] = {m[0], m[1], m[2], m[3]};
    block_max4(mx, red);
    float p[4];
    #pragma unroll
    for (int q = 0; q < 4; ++q) p[q] = __expf(m[q] - mx[q]);
    float s[4] = {p[0], p[1], p[2], p[3]};
    block_sum4(s, red);
    #pragma unroll
    for (int q = 0; q < 4; ++q)
        att[((long long)(b * NN + i0 + q)) * NN + j] = __float2bfloat16(p[q] / s[q] * a[q]);
}

// ---------------------------------------------------------------------------
// Launch: 8 kernels, no prep.
// ---------------------------------------------------------------------------
extern "C" void kernel_launch(void* const* d_in, const int* in_sizes, int n_in,
                              void* d_out, int out_size, void* d_ws, size_t ws_size,
                              hipStream_t stream)
{
    const float* feature = (const float*)d_in[0];
    const float* adj     = (const float*)d_in[1];
    const float* W0      = (const float*)d_in[2];
    const float* b0      = (const float*)d_in[3];
    const float* W1      = (const float*)d_in[4];
    const float* b1      = (const float*)d_in[5];
    const float* aW1     = (const float*)d_in[6];
    const float* ab1     = (const float*)d_in[7];
    const float* aW2     = (const float*)d_in[8];
    const float* ab2     = (const float*)d_in[9];
    float* out = (float*)d_out;

    __hip_bfloat16* bw = (__hip_bfloat16*)d_ws;
    __hip_bfloat16* xb  = bw;                        // 1024*640 (layer-2 input)
    __hip_bfloat16* hb  = xb + MROWS * KPAD;         // 1024*640
    __hip_bfloat16* hT  = hb + MROWS * KPAD;         // 4*640*256
    __hip_bfloat16* att = hT + BATCH * KPAD * NN;    // 4*256*256
    float* LR = (float*)(att + BATCH * NN * NN);     // 1024*512 fp32

    for (int layer = 0; layer < 2; ++layer) {
        const float* W  = layer ? W1 : W0;
        const float* bb = layer ? b1 : b0;

        // hb = x @ W + b  [1024][640] bf16 ; also hT[b][d][j]
        if (layer == 0) {
            gemm_cvt<true, false, false, true, true, false, KPAD/64>
                <<<dim3(KPAD / 64, MROWS / 64), 256, 0, stream>>>(
                feature, W, bb, nullptr, hb, hT,
                DD, 0, KPAD, 0, DD);
        } else {
            gemm_cvt<false, false, false, true, true, false, KPAD/64>
                <<<dim3(KPAD / 64, MROWS / 64), 256, 0, stream>>>(
                xb, W, bb, nullptr, hb, hT,
                KPAD, 0, KPAD, 0, DD);
        }

        // LR = hb @ [aW1 left | right] (+ab1 on cols<256)  [1024][512] fp32
        gemm_cvt<false, false, true, false, false, true, KPAD/64>
            <<<dim3(512 / 64, MROWS / 64), 256, 0, stream>>>(
            hb, aW1, ab1, LR, nullptr, nullptr,
            KPAD, 512, 0, 512, HH);

        // att = softmax(mask(leaky(score))) * adj   bf16
        attn_kernel<<<dim3(NN / 4, BATCH), 256, 0, stream>>>(LR, aW2, ab2, adj, att);

        // out = relu(att @ h): layer0 -> xb (bf16); layer1 -> out fp32
        if (layer == 0) {
            gemm_mfma<true, false, true, NN/64>
                <<<dim3(KPAD / 64, NN / 64, BATCH), 256, 0, stream>>>(
                att, hT, nullptr, xb,
                NN, NN, 0, KPAD, 0,
                (long long)NN * NN, (long long)KPAD * NN, 0, (long long)NN * KPAD);
        } else {
            gemm_mfma<true, true, false, NN/64>
                <<<dim3(KPAD / 64, NN / 64, BATCH), 256, 0, stream>>>(
                att, hT, out, nullptr,
                NN, NN, DD, 0, DD,
                (long long)NN * NN, (long long)KPAD * NN, (long long)NN * DD, 0);
        }
    }
}

// Round 10
// 85.650 us; speedup vs baseline: 1.6834x; 1.6834x over previous
//
#include <hip/hip_runtime.h>
#include <hip/hip_bf16.h>

// ---------------------------------------------------------------------------
// Sizes (fixed)
// ---------------------------------------------------------------------------
#define BATCH 4
#define NN    256
#define DD    600
#define HH    256
#define MROWS (BATCH*NN)   // 1024
#define KPAD  640          // DD padded to multiple of 64
#define NFUSE 1152         // 640 (h) + 256 (L) + 256 (R)

typedef __attribute__((ext_vector_type(8))) short bf16x8;   // 8 bf16 (4 VGPRs)
typedef __attribute__((ext_vector_type(4))) float f32x4;

__device__ __forceinline__ void gload16(const void* g, void* l)
{
    __builtin_amdgcn_global_load_lds(
        (const __attribute__((address_space(1))) void*)g,
        (__attribute__((address_space(3))) void*)l, 16, 0, 0);
}

__device__ __forceinline__ void waitcnt_vm(int n)
{
    switch (n) {
    case 0:  asm volatile("s_waitcnt vmcnt(0)"  ::: "memory"); break;
    case 4:  asm volatile("s_waitcnt vmcnt(4)"  ::: "memory"); break;
    case 8:  asm volatile("s_waitcnt vmcnt(8)"  ::: "memory"); break;
    default: asm volatile("s_waitcnt vmcnt(0)"  ::: "memory"); break;
    }
}

// XCD-chunked bijective remap (m204) of flattened block id
__device__ __forceinline__ int xcd_remap(int lin, int nwg)
{
    const int q = nwg >> 3, r = nwg & 7;
    const int xcd = lin & 7, off = lin >> 3;
    return (xcd < r ? xcd * (q + 1) : r * (q + 1) + (xcd - r) * q) + off;
}

// ---------------------------------------------------------------------------
// bf16 MFMA GEMM: C = A[M,K] @ BT^T (+bias cols<biasN) (+relu), K = NK*64.
// Tile 64x64x64, 4 waves (2x2). Ring-4 LDS, counted vmcnt + raw s_barrier.
// Non-fused: WF32 fp32 C (cols<Nvalid); WB16 bf16 C; WHT hT retile.
// FUSEDLR epilogue (hLR kernel, z==1):
//   col0 <  640 : bf16 hb (+sT retile -> hT[b][d][j])
//   col0 <  896 : fp32 LRL[row][gc-640]        (L + ab1 via bias)
//   col0 >= 896 : fp32 RT[b][gc-896][row&255]  (R, transposed, float4 store)
// ---------------------------------------------------------------------------
template<bool BIAS, bool RELU, bool WF32, bool WB16, bool WHT, bool FUSEDLR, int NK>
__global__ __launch_bounds__(256) void gemm_mfma(
    const __hip_bfloat16* __restrict__ A, const __hip_bfloat16* __restrict__ BT,
    const float* __restrict__ bias,
    float* __restrict__ Cf, __hip_bfloat16* __restrict__ Cb,
    __hip_bfloat16* __restrict__ hT, float* __restrict__ RT,
    int lda, int ldb, int ldcf, int ldcb, int Nvalid, int biasN,
    long long sA, long long sBT, long long sCf, long long sCb)
{
    __shared__ __align__(16) char lds[65536];   // ring: A at (t&3)*8K, B at 32K+(t&3)*8K

    const int nwg = gridDim.x * gridDim.y * gridDim.z;
    int lin = xcd_remap(blockIdx.x + gridDim.x * (blockIdx.y + gridDim.y * blockIdx.z), nwg);
    const int bx = lin % gridDim.x;
    const int by = (lin / gridDim.x) % gridDim.y;
    const int bz = lin / (gridDim.x * gridDim.y);

    const int tid  = threadIdx.x;
    const int lane = tid & 63;
    const int wid  = tid >> 6;
    const int wr   = wid >> 1;
    const int wc   = wid & 1;
    const int row0 = by * 64;
    const int col0 = bx * 64;

    const char* Ab = (const char*)A + (bz * sA + (long long)row0 * lda) * 2;
    const char* Bb = (const char*)BT + (bz * sBT + (long long)col0 * ldb) * 2;

    const int sr   = tid >> 3;                    // 0..31
    const int scb  = (tid & 7) * 16;              // 0..112
    const int scbs = scb ^ ((sr & 7) << 4);       // inverse source swizzle

    const char* gA0 = Ab + (long long)sr        * (lda * 2) + scbs;
    const char* gA1 = Ab + (long long)(sr + 32) * (lda * 2) + scbs;
    const char* gB0 = Bb + (long long)sr        * (ldb * 2) + scbs;
    const char* gB1 = Bb + (long long)(sr + 32) * (ldb * 2) + scbs;

    f32x4 acc[2][2] = {};
    const int fr = lane & 15;
    const int kg = (lane >> 4) * 16;
    const int xv = (fr & 7) << 4;       // read-side XOR swizzle

    auto issue = [&](int t) {
        char* bA = lds + (t & 3) * 8192;
        char* bB = lds + 32768 + (t & 3) * 8192;
        const long long off = (long long)t * 128;
        gload16(gA0 + off, bA + wid * 1024);
        gload16(gA1 + off, bA + 4096 + wid * 1024);
        gload16(gB0 + off, bB + wid * 1024);
        gload16(gB1 + off, bB + 4096 + wid * 1024);
    };

    constexpr int PRE = (NK < 3) ? NK : 3;
    #pragma unroll
    for (int p = 0; p < PRE; ++p) issue(p);

    #pragma unroll
    for (int t = 0; t < NK; ++t) {
        const int imax = (t + 2 < NK - 1) ? t + 2 : NK - 1;
        waitcnt_vm(4 * (imax - t));
        __builtin_amdgcn_s_barrier();
        const char* lA = lds + (t & 3) * 8192;
        const char* lB = lds + 32768 + (t & 3) * 8192;
        #pragma unroll
        for (int ks = 0; ks < 2; ++ks) {
            const int kb = ks * 64 + kg;
            bf16x8 a0 = *(const bf16x8*)(lA + (wr * 32 + fr)      * 128 + (kb ^ xv));
            bf16x8 a1 = *(const bf16x8*)(lA + (wr * 32 + 16 + fr) * 128 + (kb ^ xv));
            bf16x8 b0 = *(const bf16x8*)(lB + (wc * 32 + fr)      * 128 + (kb ^ xv));
            bf16x8 b1 = *(const bf16x8*)(lB + (wc * 32 + 16 + fr) * 128 + (kb ^ xv));
            acc[0][0] = __builtin_amdgcn_mfma_f32_16x16x32_bf16(a0, b0, acc[0][0], 0, 0, 0);
            acc[0][1] = __builtin_amdgcn_mfma_f32_16x16x32_bf16(a0, b1, acc[0][1], 0, 0, 0);
            acc[1][0] = __builtin_amdgcn_mfma_f32_16x16x32_bf16(a1, b0, acc[1][0], 0, 0, 0);
            acc[1][1] = __builtin_amdgcn_mfma_f32_16x16x32_bf16(a1, b1, acc[1][1], 0, 0, 0);
        }
        if (t + 3 < NK) issue(t + 3);
    }
    __syncthreads();                     // all LDS reads done (sT reuse below)

    // epilogue: C/D frag mapping col=lane&15, row=(lane>>4)*4+reg
    const int er = (lane >> 4) * 4;
    const int ec = lane & 15;
    __hip_bfloat16* sT = (__hip_bfloat16*)lds;   // [64][72] retile buffer

    if constexpr (FUSEDLR) {
        if (col0 >= 896) {
            // R half -> fp32 RT[b][h'][j], one float4 per quadrant
            #pragma unroll
            for (int mi = 0; mi < 2; ++mi) {
                #pragma unroll
                for (int ni = 0; ni < 2; ++ni) {
                    const int gr = row0 + wr * 32 + mi * 16 + er;
                    const int gc = col0 + wc * 32 + ni * 16 + ec;
                    const float bv = bias[gc];
                    f32x4 q = acc[mi][ni];
                    float4 o = make_float4(q[0] + bv, q[1] + bv, q[2] + bv, q[3] + bv);
                    const int b = gr >> 8, j = gr & 255;
                    *(float4*)&RT[((long long)(b * 256 + (gc - 896))) * 256 + j] = o;
                }
            }
        } else if (col0 >= 640) {
            // L half -> fp32 LRL[row][h']  (ab1 folded via bias)
            #pragma unroll
            for (int mi = 0; mi < 2; ++mi) {
                #pragma unroll
                for (int ni = 0; ni < 2; ++ni) {
                    const int gr = row0 + wr * 32 + mi * 16 + er;
                    const int gc = col0 + wc * 32 + ni * 16 + ec;
                    const float bv = bias[gc];
                    #pragma unroll
                    for (int r = 0; r < 4; ++r)
                        Cf[(long long)(gr + r) * ldcf + (gc - 640)] = acc[mi][ni][r] + bv;
                }
            }
        } else {
            // h half -> bf16 hb + sT retile
            #pragma unroll
            for (int mi = 0; mi < 2; ++mi) {
                #pragma unroll
                for (int ni = 0; ni < 2; ++ni) {
                    const int lr0 = wr * 32 + mi * 16 + er;
                    const int lc  = wc * 32 + ni * 16 + ec;
                    const int gr = row0 + lr0;
                    const int gc = col0 + lc;
                    const float bv = bias[gc];
                    #pragma unroll
                    for (int r = 0; r < 4; ++r) {
                        const __hip_bfloat16 hv = __float2bfloat16(acc[mi][ni][r] + bv);
                        Cb[(long long)(gr + r) * ldcb + gc] = hv;
                        sT[(lr0 + r) * 72 + lc] = hv;
                    }
                }
            }
            __syncthreads();
            const int b  = row0 >> 8;
            const int i0 = row0 & 255;
            const int cc = tid >> 3;
            const int ch = tid & 7;
            #pragma unroll
            for (int p = 0; p < 2; ++p) {
                const int d = col0 + cc + p * 32;
                __align__(16) __hip_bfloat16 tmp[8];
                #pragma unroll
                for (int u = 0; u < 8; ++u)
                    tmp[u] = sT[(ch * 8 + u) * 72 + cc + p * 32];
                *(float4*)&hT[((long long)b * KPAD + d) * NN + i0 + ch * 8] = *(float4*)tmp;
            }
        }
    } else {
        #pragma unroll
        for (int mi = 0; mi < 2; ++mi) {
            #pragma unroll
            for (int ni = 0; ni < 2; ++ni) {
                const int lr0 = wr * 32 + mi * 16 + er;
                const int lc  = wc * 32 + ni * 16 + ec;
                const int gr = row0 + lr0;
                const int gc = col0 + lc;
                const float bv = (BIAS && gc < biasN) ? bias[gc] : 0.f;
                #pragma unroll
                for (int r = 0; r < 4; ++r) {
                    float v = acc[mi][ni][r] + bv;
                    if (RELU) v = fmaxf(v, 0.f);
                    const __hip_bfloat16 hv = __float2bfloat16(v);
                    const long long row = gr + r;
                    if (WF32 && gc < Nvalid)
                        Cf[bz * sCf + row * ldcf + gc] = v;
                    if (WB16)
                        Cb[bz * sCb + row * ldcb + gc] = hv;
                    if (WHT)
                        sT[(lr0 + r) * 72 + lc] = hv;
                }
            }
        }
        if (WHT) {
            __syncthreads();
            const int b  = row0 >> 8;
            const int i0 = row0 & 255;
            const int cc = tid >> 3;
            const int ch = tid & 7;
            #pragma unroll
            for (int p = 0; p < 2; ++p) {
                const int d = col0 + cc + p * 32;
                __align__(16) __hip_bfloat16 tmp[8];
                #pragma unroll
                for (int u = 0; u < 8; ++u)
                    tmp[u] = sT[(ch * 8 + u) * 72 + cc + p * 32];
                *(float4*)&hT[((long long)b * KPAD + d) * NN + i0 + ch * 8] = *(float4*)tmp;
            }
        }
    }
}

// ---------------------------------------------------------------------------
// Prep kernel. Unit map (blockIdx.x), 2569 blocks:
//  [0,640)      xb = bf16(pad(feature))
//  [640,1040)   UT0 rows 0..639 = W0^T (32x32 LDS transpose)
//  [1040,1440)  UT1 rows 0..639 = W1^T
//  [1440,1760)  aW1T[512][640] = packed aW1^T (left rows 0..255, right 256..511)
//  [1760,2160)  Wb[0] = bf16(W0) row-major padded
//  [2160,2560)  Wb[1] = bf16(W1)
//  [2560,2564)  biasLR: fb_l[640+256p+n'] = b_l . aW1p[:,n'] (+ab1 if p==0)
//  [2564,2569)  fbias base: fb_l[c<640] = (c<600 ? b_l[c] : 0)
// ---------------------------------------------------------------------------
__global__ __launch_bounds__(256) void prep_kernel(
    const float* __restrict__ feature, const float* __restrict__ W0,
    const float* __restrict__ W1, const float* __restrict__ aW1,
    const float* __restrict__ b0, const float* __restrict__ b1,
    const float* __restrict__ ab1,
    __hip_bfloat16* __restrict__ xb, __hip_bfloat16* __restrict__ UT,
    __hip_bfloat16* __restrict__ aW1T, __hip_bfloat16* __restrict__ Wb,
    float* __restrict__ fb)
{
    const int u   = blockIdx.x;
    const int tid = threadIdx.x;

    if (u < 640) {                      // xb
        const int idx = (u * 256 + tid) * 4;
        const int r = idx / KPAD, c = idx % KPAD;
        float4 v = make_float4(0.f, 0.f, 0.f, 0.f);
        if (c < DD) v = *(const float4*)&feature[r * DD + c];   // DD%4==0
        __align__(8) __hip_bfloat16 o[4] = {
            __float2bfloat16(v.x), __float2bfloat16(v.y),
            __float2bfloat16(v.z), __float2bfloat16(v.w)};
        *(float2*)&xb[idx] = *(float2*)o;
        return;
    }
    if (u < 1760) {                     // transposes (W0T, W1T, aW1T)
        __shared__ float tile[32][33];
        const int t = u - 640;
        const int which = (t < 400) ? 0 : (t < 800) ? 1 : 2;
        const int tt = (which == 0) ? t : (which == 1) ? t - 400 : t - 800;
        const int n0 = (tt / 20) * 32;
        const int k0 = (tt % 20) * 32;
        const int tx = tid & 31, ty = tid >> 5;
        #pragma unroll
        for (int r = 0; r < 4; ++r) {
            const int k = k0 + ty + r * 8;
            const int n = n0 + tx;
            float v = 0.f;
            if (which == 0)      { if (k < DD && n < DD) v = W0[k * DD + n]; }
            else if (which == 1) { if (k < DD && n < DD) v = W1[k * DD + n]; }
            else                 { if (k < DD) v = (n < HH) ? aW1[k * HH + n]
                                                            : aW1[(DD + k) * HH + (n - HH)]; }
            tile[ty + r * 8][tx] = v;
        }
        __syncthreads();
        __hip_bfloat16* dst = (which == 0) ? UT
                            : (which == 1) ? UT + (long long)NFUSE * KPAD
                            : aW1T;
        #pragma unroll
        for (int r = 0; r < 4; ++r) {
            const int n = n0 + ty + r * 8;
            const int k = k0 + tx;
            dst[(long long)n * KPAD + k] = __float2bfloat16(tile[tx][ty + r * 8]);
        }
        return;
    }
    if (u < 2560) {                     // Wb row-major cvt
        const int t = u - 1760;
        const int which = (t < 400) ? 0 : 1;
        const int tt = which ? t - 400 : t;
        const float* W = which ? W1 : W0;
        const int idx = (tt * 256 + tid) * 4;
        const int i = idx / KPAD, o = idx % KPAD;
        float4 v = make_float4(0.f, 0.f, 0.f, 0.f);
        if (i < DD && o < DD) v = *(const float4*)&W[i * DD + o];
        __align__(8) __hip_bfloat16 ob[4] = {
            __float2bfloat16(v.x), __float2bfloat16(v.y),
            __float2bfloat16(v.z), __float2bfloat16(v.w)};
        *(float2*)&Wb[(long long)which * KPAD * KPAD + idx] = *(float2*)ob;
        return;
    }
    if (u < 2564) {                     // biasLR
        const int idx = u - 2560;
        const int l = idx >> 1, p = idx & 1;
        const float* bl = l ? b1 : b0;
        float acc = 0.f;
        for (int d = 0; d < DD; ++d)
            acc += bl[d] * aW1[(long long)(d + DD * p) * HH + tid];
        fb[l * NFUSE + 640 + p * 256 + tid] = acc + (p == 0 ? ab1[tid] : 0.f);
        return;
    }
    {                                   // fbias base
        const int e = (u - 2564) * 256 + tid;   // 0..1279
        const int l = e / 640, c = e % 640;
        const float* bl = l ? b1 : b0;
        fb[l * NFUSE + c] = (c < DD) ? bl[c] : 0.f;
    }
}

// ---------------------------------------------------------------------------
// Attention: score + leaky_relu + mask + softmax + *adj -> att (bf16)
// Block = (b, 4 rows i); thread j. L from LRL[1024][256]; R from RT[b][h][j]
// (coalesced across j). adj prefetched before the h-loop.
// ---------------------------------------------------------------------------
__device__ __forceinline__ void block_max4(float* v, float (*red)[4])
{
    #pragma unroll
    for (int o = 32; o > 0; o >>= 1)
        #pragma unroll
        for (int q = 0; q < 4; ++q) v[q] = fmaxf(v[q], __shfl_down(v[q], o));
    const int lane = threadIdx.x & 63, w = threadIdx.x >> 6;
    if (lane == 0) { red[w][0]=v[0]; red[w][1]=v[1]; red[w][2]=v[2]; red[w][3]=v[3]; }
    __syncthreads();
    #pragma unroll
    for (int q = 0; q < 4; ++q)
        v[q] = fmaxf(fmaxf(red[0][q], red[1][q]), fmaxf(red[2][q], red[3][q]));
    __syncthreads();
}

__device__ __forceinline__ void block_sum4(float* v, float (*red)[4])
{
    #pragma unroll
    for (int o = 32; o > 0; o >>= 1)
        #pragma unroll
        for (int q = 0; q < 4; ++q) v[q] += __shfl_down(v[q], o);
    const int lane = threadIdx.x & 63, w = threadIdx.x >> 6;
    if (lane == 0) { red[w][0]=v[0]; red[w][1]=v[1]; red[w][2]=v[2]; red[w][3]=v[3]; }
    __syncthreads();
    #pragma unroll
    for (int q = 0; q < 4; ++q)
        v[q] = red[0][q] + red[1][q] + red[2][q] + red[3][q];
    __syncthreads();
}

__global__ __launch_bounds__(256) void attn_kernel(
    const float* __restrict__ LRL, const float* __restrict__ RT,
    const float* __restrict__ aW2, const float* __restrict__ ab2,
    const float* __restrict__ adj, __hip_bfloat16* __restrict__ att)
{
    __shared__ float sL[4][HH];
    __shared__ float sW[HH];
    __shared__ float red[4][4];

    const int b  = blockIdx.y;
    const int i0 = blockIdx.x * 4;
    const int j  = threadIdx.x;

    float a[4];
    #pragma unroll
    for (int q = 0; q < 4; ++q)
        a[q] = adj[((long long)(b * NN + i0 + q)) * NN + j];
    const float ab2v = ab2[0];

    sW[j] = aW2[j];
    #pragma unroll
    for (int q = 0; q < 4; ++q)
        sL[q][j] = LRL[((long long)(b * NN + i0 + q)) * HH + j];
    __syncthreads();

    const float* rp = RT + (long long)b * HH * NN + j;
    float acc[4] = {0.f, 0.f, 0.f, 0.f};
    for (int h = 0; h < HH; h += 8) {
        float rv[8];
        #pragma unroll
        for (int u = 0; u < 8; ++u) rv[u] = rp[(h + u) * NN];   // coalesced across j
        const float4 w0 = *(const float4*)&sW[h];
        const float4 w1 = *(const float4*)&sW[h + 4];
        #pragma unroll
        for (int q = 0; q < 4; ++q) {
            const float4 l0 = *(const float4*)&sL[q][h];
            const float4 l1 = *(const float4*)&sL[q][h + 4];
            float s = fmaxf(l0.x + rv[0], 0.f) * w0.x;
            s += fmaxf(l0.y + rv[1], 0.f) * w0.y;
            s += fmaxf(l0.z + rv[2], 0.f) * w0.z;
            s += fmaxf(l0.w + rv[3], 0.f) * w0.w;
            s += fmaxf(l1.x + rv[4], 0.f) * w1.x;
            s += fmaxf(l1.y + rv[5], 0.f) * w1.y;
            s += fmaxf(l1.z + rv[6], 0.f) * w1.z;
            s += fmaxf(l1.w + rv[7], 0.f) * w1.w;
            acc[q] += s;
        }
    }

    float m[4];
    #pragma unroll
    for (int q = 0; q < 4; ++q) {
        float e = acc[q] + ab2v;
        e = (e > 0.f) ? e : 0.01f * e;                       // leaky_relu
        m[q] = (a[q] == 0.f) ? -1e9f : e;                    // mask
    }
    float mx[4] = {m[0], m[1], m[2], m[3]};
    block_max4(mx, red);
    float p[4];
    #pragma unroll
    for (int q = 0; q < 4; ++q) p[q] = __expf(m[q] - mx[q]);
    float s[4] = {p[0], p[1], p[2], p[3]};
    block_sum4(s, red);
    #pragma unroll
    for (int q = 0; q < 4; ++q)
        att[((long long)(b * NN + i0 + q)) * NN + j] = __float2bfloat16(p[q] / s[q] * a[q]);
}

// ---------------------------------------------------------------------------
// Launch: 8 kernels (prep, wa, then per layer: fused hLR, attn, out)
// ---------------------------------------------------------------------------
extern "C" void kernel_launch(void* const* d_in, const int* in_sizes, int n_in,
                              void* d_out, int out_size, void* d_ws, size_t ws_size,
                              hipStream_t stream)
{
    const float* feature = (const float*)d_in[0];
    const float* adj     = (const float*)d_in[1];
    const float* W0      = (const float*)d_in[2];
    const float* b0      = (const float*)d_in[3];
    const float* W1      = (const float*)d_in[4];
    const float* b1      = (const float*)d_in[5];
    const float* aW1     = (const float*)d_in[6];
    const float* ab1     = (const float*)d_in[7];
    const float* aW2     = (const float*)d_in[8];
    const float* ab2     = (const float*)d_in[9];
    float* out = (float*)d_out;

    const long long UTsz = (long long)NFUSE * KPAD;
    __hip_bfloat16* bw = (__hip_bfloat16*)d_ws;
    __hip_bfloat16* xb   = bw;                        // 1024*640
    __hip_bfloat16* UT   = xb   + MROWS * KPAD;       // 2*1152*640
    __hip_bfloat16* aW1T = UT   + 2 * UTsz;           // 512*640
    __hip_bfloat16* Wb   = aW1T + 512 * KPAD;         // 2*640*640
    __hip_bfloat16* hb   = Wb   + 2 * KPAD * KPAD;    // 1024*640
    __hip_bfloat16* hT   = hb   + MROWS * KPAD;       // 4*640*256
    __hip_bfloat16* att  = hT   + BATCH * KPAD * NN;  // 4*256*256
    float* LRL = (float*)(att + BATCH * NN * NN);     // 1024*256 fp32
    float* RT  = LRL + MROWS * HH;                    // 4*256*256 fp32
    float* fb  = RT  + BATCH * HH * NN;               // 2*1152 fp32

    prep_kernel<<<2569, 256, 0, stream>>>(
        feature, W0, W1, aW1, b0, b1, ab1, xb, UT, aW1T, Wb, fb);

    // wa: UT{l} rows 640..1151 = Wa_l^T = aW1T @ Wb{l}   (z=2 batched)
    gemm_mfma<false, false, false, true, false, false, KPAD/64>
        <<<dim3(KPAD / 64, 512 / 64, 2), 256, 0, stream>>>(
        aW1T, Wb, nullptr, nullptr, UT + (long long)KPAD * KPAD, nullptr, nullptr,
        KPAD, KPAD, 0, KPAD, 0, 0,
        0, (long long)KPAD * KPAD, 0, UTsz);

    for (int layer = 0; layer < 2; ++layer) {
        // fused hLR: [hb | L | R] = x @ UT{l}^T + fb{l}
        gemm_mfma<true, false, false, false, false, true, KPAD/64>
            <<<dim3(NFUSE / 64, MROWS / 64, 1), 256, 0, stream>>>(
            xb, UT + layer * UTsz, fb + layer * NFUSE, LRL, hb, hT, RT,
            KPAD, KPAD, HH, KPAD, 0, NFUSE, 0, 0, 0, 0);

        // att = softmax(mask(leaky(score))) * adj   bf16
        attn_kernel<<<dim3(NN / 4, BATCH), 256, 0, stream>>>(LRL, RT, aW2, ab2, adj, att);

        // out = relu(att @ h): layer0 -> xb (bf16); layer1 -> out fp32
        if (layer == 0) {
            gemm_mfma<false, true, false, true, false, false, NN/64>
                <<<dim3(KPAD / 64, NN / 64, BATCH), 256, 0, stream>>>(
                att, hT, nullptr, nullptr, xb, nullptr, nullptr,
                NN, NN, 0, KPAD, 0, 0,
                (long long)NN * NN, (long long)KPAD * NN, 0, (long long)NN * KPAD);
        } else {
            gemm_mfma<false, true, true, false, false, false, NN/64>
                <<<dim3(KPAD / 64, NN / 64, BATCH), 256, 0, stream>>>(
                att, hT, nullptr, out, nullptr, nullptr, nullptr,
                NN, NN, DD, 0, DD, 0,
                (long long)NN * NN, (long long)KPAD * NN, (long long)NN * DD, 0);
        }
    }
}

// Round 11
// 64.688 us; speedup vs baseline: 2.2289x; 1.3240x over previous
//
#include <hip/hip_runtime.h>
#include <hip/hip_bf16.h>

// ---------------------------------------------------------------------------
// Sizes (fixed)
// ---------------------------------------------------------------------------
#define BATCH 4
#define NN    256
#define DD    600
#define HH    256
#define MROWS (BATCH*NN)   // 1024
#define KPAD  640          // DD padded to multiple of 64

typedef __attribute__((ext_vector_type(8))) short bf16x8;   // 8 bf16 (4 VGPRs)
typedef __attribute__((ext_vector_type(4))) float f32x4;

__device__ __forceinline__ void gload16(const void* g, void* l)
{
    __builtin_amdgcn_global_load_lds(
        (const __attribute__((address_space(1))) void*)g,
        (__attribute__((address_space(3))) void*)l, 16, 0, 0);
}

// counted vmcnt wait; n is compile-time after full unroll -> folds to one inst
__device__ __forceinline__ void waitcnt_vm(int n)
{
    switch (n) {
    case 0:  asm volatile("s_waitcnt vmcnt(0)"  ::: "memory"); break;
    case 3:  asm volatile("s_waitcnt vmcnt(3)"  ::: "memory"); break;
    case 6:  asm volatile("s_waitcnt vmcnt(6)"  ::: "memory"); break;
    default: asm volatile("s_waitcnt vmcnt(0)"  ::: "memory"); break;
    }
}

// XCD-chunked bijective remap (m204) of flattened block id
__device__ __forceinline__ int xcd_remap(int lin, int nwg)
{
    const int q = nwg >> 3, r = nwg & 7;
    const int xcd = lin & 7, off = lin >> 3;
    return (xcd < r ? xcd * (q + 1) : r * (q + 1) + (xcd - r) * q) + off;
}

// ---------------------------------------------------------------------------
// bf16 MFMA GEMM: C = A[M,K] @ BT^T (+bias cols<biasN) (+relu), K = NK*64.
// Tile 64M x 32N x 64K, 256 threads = 4 waves (2x2), wave tile 32x16.
// Ring-4 LDS (A 8K x4 + B 4K x4 = 48 KB); 3 gload_lds issues per k-tile;
// counted vmcnt (3 per in-flight tile) + raw s_barrier (T3/T4).
// Grid x = N/32, y = M/64 (z batches). ~2x block count of the 64x64 version
// -> all 256 CUs occupied (latency-bound regime).
// WF32: fp32 C (cols<Nvalid). WB16: bf16 C (all cols).
// WHT: also write hT[b][d][j] via LDS retile (M must be 1024 = 4b x 256j).
// LDS XOR-swizzle (T2/m201): linear global_load_lds dest + inverse-swizzled
// global source + swizzled ds_read_b128.
// ---------------------------------------------------------------------------
template<bool BIAS, bool RELU, bool WF32, bool WB16, bool WHT, int NK>
__global__ __launch_bounds__(256) void gemm_mfma(
    const __hip_bfloat16* __restrict__ A, const __hip_bfloat16* __restrict__ BT,
    const float* __restrict__ bias,
    float* __restrict__ Cf, __hip_bfloat16* __restrict__ Cb,
    __hip_bfloat16* __restrict__ hT,
    int lda, int ldb, int ldcf, int ldcb, int Nvalid, int biasN,
    long long sA, long long sBT, long long sCf, long long sCb)
{
    __shared__ __align__(16) char lds[49152];   // A: (t&3)*8K ; B: 32K+(t&3)*4K

    const int nwg = gridDim.x * gridDim.y * gridDim.z;
    int lin = xcd_remap(blockIdx.x + gridDim.x * (blockIdx.y + gridDim.y * blockIdx.z), nwg);
    const int bx = lin % gridDim.x;
    const int by = (lin / gridDim.x) % gridDim.y;
    const int bz = lin / (gridDim.x * gridDim.y);

    const int tid  = threadIdx.x;
    const int lane = tid & 63;
    const int wid  = tid >> 6;
    const int wr   = wid >> 1;          // wave row 0..1 (32 M each)
    const int wc   = wid & 1;           // wave col 0..1 (16 N each)
    const int row0 = by * 64;
    const int col0 = bx * 32;

    const char* Ab = (const char*)A + (bz * sA + (long long)row0 * lda) * 2;
    const char* Bb = (const char*)BT + (bz * sBT + (long long)col0 * ldb) * 2;

    const int sr   = tid >> 3;                    // 0..31
    const int scb  = (tid & 7) * 16;              // 0..112
    const int scbs = scb ^ ((sr & 7) << 4);       // inverse source swizzle

    const char* gA0 = Ab + (long long)sr        * (lda * 2) + scbs;
    const char* gA1 = Ab + (long long)(sr + 32) * (lda * 2) + scbs;
    const char* gB0 = Bb + (long long)sr        * (ldb * 2) + scbs;

    f32x4 acc[2] = {};
    const int fr = lane & 15;
    const int kg = (lane >> 4) * 16;
    const int xv = (fr & 7) << 4;       // read-side XOR swizzle

    auto issue = [&](int t) {
        char* bA = lds + (t & 3) * 8192;
        char* bB = lds + 32768 + (t & 3) * 4096;
        const long long off = (long long)t * 128;
        gload16(gA0 + off, bA + wid * 1024);
        gload16(gA1 + off, bA + 4096 + wid * 1024);
        gload16(gB0 + off, bB + wid * 1024);
    };

    constexpr int PRE = (NK < 3) ? NK : 3;
    #pragma unroll
    for (int p = 0; p < PRE; ++p) issue(p);

    #pragma unroll
    for (int t = 0; t < NK; ++t) {
        const int imax = (t + 2 < NK - 1) ? t + 2 : NK - 1;   // last issued tile
        waitcnt_vm(3 * (imax - t));          // tile t's 3 loads complete
        __builtin_amdgcn_s_barrier();        // all waves' loads for tile t landed
        const char* lA = lds + (t & 3) * 8192;
        const char* lB = lds + 32768 + (t & 3) * 4096;
        #pragma unroll
        for (int ks = 0; ks < 2; ++ks) {
            const int kb = ks * 64 + kg;
            bf16x8 a0 = *(const bf16x8*)(lA + (wr * 32 + fr)      * 128 + (kb ^ xv));
            bf16x8 a1 = *(const bf16x8*)(lA + (wr * 32 + 16 + fr) * 128 + (kb ^ xv));
            bf16x8 b0 = *(const bf16x8*)(lB + (wc * 16 + fr)      * 128 + (kb ^ xv));
            acc[0] = __builtin_amdgcn_mfma_f32_16x16x32_bf16(a0, b0, acc[0], 0, 0, 0);
            acc[1] = __builtin_amdgcn_mfma_f32_16x16x32_bf16(a1, b0, acc[1], 0, 0, 0);
        }
        if (t + 3 < NK) issue(t + 3);        // into buffer (t-1)&3: reads done pre-barrier
    }
    __syncthreads();                          // all LDS reads done (sT reuse below)

    // epilogue: C/D frag mapping col=lane&15, row=(lane>>4)*4+reg
    const int er = (lane >> 4) * 4;
    const int ec = lane & 15;
    __hip_bfloat16* sT = (__hip_bfloat16*)lds;   // [64][40] retile buffer

    #pragma unroll
    for (int mi = 0; mi < 2; ++mi) {
        const int lr0 = wr * 32 + mi * 16 + er;
        const int lc  = wc * 16 + ec;
        const int gr = row0 + lr0;
        const int gc = col0 + lc;
        const float bv = (BIAS && gc < biasN) ? bias[gc] : 0.f;
        #pragma unroll
        for (int r = 0; r < 4; ++r) {
            float v = acc[mi][r] + bv;
            if (RELU) v = fmaxf(v, 0.f);
            const __hip_bfloat16 hv = __float2bfloat16(v);
            const long long row = gr + r;
            if (WF32 && gc < Nvalid)
                Cf[bz * sCf + row * ldcf + gc] = v;
            if (WB16)
                Cb[bz * sCb + row * ldcb + gc] = hv;
            if (WHT)
                sT[(lr0 + r) * 40 + lc] = hv;
        }
    }

    if (WHT) {
        __syncthreads();
        const int b  = row0 >> 8;
        const int i0 = row0 & 255;
        const int cc = tid >> 3;         // 0..31 (d within tile)
        const int ch = tid & 7;          // j-chunk of 8
        const int d = col0 + cc;
        __align__(16) __hip_bfloat16 tmp[8];
        #pragma unroll
        for (int u = 0; u < 8; ++u)
            tmp[u] = sT[(ch * 8 + u) * 40 + cc];
        *(float4*)&hT[((long long)b * KPAD + d) * NN + i0 + ch * 8] = *(float4*)tmp;
    }
}

// ---------------------------------------------------------------------------
// Prep: xb = bf16(pad(feature)) vectorized; W0T/W1T/aW1T via 32x32 LDS
// tile transpose (coalesced both sides) + bf16 convert.
// ---------------------------------------------------------------------------
__global__ __launch_bounds__(256) void prep_kernel(
    const float* __restrict__ feature, const float* __restrict__ W0,
    const float* __restrict__ W1, const float* __restrict__ aW1,
    __hip_bfloat16* __restrict__ xb, __hip_bfloat16* __restrict__ W0T,
    __hip_bfloat16* __restrict__ W1T, __hip_bfloat16* __restrict__ aW1T)
{
    const int bid = blockIdx.x;
    const int tid = threadIdx.x;
    if (bid < 640) {
        const int idx = (bid * 256 + tid) * 4;
        const int r = idx / KPAD, c = idx % KPAD;
        float4 v = make_float4(0.f, 0.f, 0.f, 0.f);
        if (c < DD) v = *(const float4*)&feature[r * DD + c];   // DD%4==0
        __align__(8) __hip_bfloat16 o[4] = {
            __float2bfloat16(v.x), __float2bfloat16(v.y),
            __float2bfloat16(v.z), __float2bfloat16(v.w)};
        *(float2*)&xb[idx] = *(float2*)o;
        return;
    }
    __shared__ float tile[32][33];
    const int t = bid - 640;
    const int which = (t < 400) ? 0 : (t < 800) ? 1 : 2;
    const int tt = (which == 0) ? t : (which == 1) ? t - 400 : t - 800;
    const int n0 = (tt / 20) * 32;
    const int k0 = (tt % 20) * 32;
    const int tx = tid & 31, ty = tid >> 5;
    #pragma unroll
    for (int r = 0; r < 4; ++r) {
        const int k = k0 + ty + r * 8;
        const int n = n0 + tx;
        float v = 0.f;
        if (which == 0)      { if (k < DD && n < DD) v = W0[k * DD + n]; }
        else if (which == 1) { if (k < DD && n < DD) v = W1[k * DD + n]; }
        else                 { if (k < DD) v = (n < HH) ? aW1[k * HH + n]
                                                        : aW1[(DD + k) * HH + (n - HH)]; }
        tile[ty + r * 8][tx] = v;
    }
    __syncthreads();
    __hip_bfloat16* dst = (which == 0) ? W0T : (which == 1) ? W1T : aW1T;
    #pragma unroll
    for (int r = 0; r < 4; ++r) {
        const int n = n0 + ty + r * 8;
        const int k = k0 + tx;
        dst[n * KPAD + k] = __float2bfloat16(tile[tx][ty + r * 8]);
    }
}

// ---------------------------------------------------------------------------
// Attention: score + leaky_relu + mask + softmax + *adj -> att (bf16)
// Block = (b, 4 rows); thread j. 256 blocks (1/CU). adj prefetched before
// the h-loop so its latency hides under the score compute.
// ---------------------------------------------------------------------------
__device__ __forceinline__ void block_max4(float* v, float (*red)[4])
{
    #pragma unroll
    for (int o = 32; o > 0; o >>= 1)
        #pragma unroll
        for (int q = 0; q < 4; ++q) v[q] = fmaxf(v[q], __shfl_down(v[q], o));
    const int lane = threadIdx.x & 63, w = threadIdx.x >> 6;
    if (lane == 0) { red[w][0]=v[0]; red[w][1]=v[1]; red[w][2]=v[2]; red[w][3]=v[3]; }
    __syncthreads();
    #pragma unroll
    for (int q = 0; q < 4; ++q)
        v[q] = fmaxf(fmaxf(red[0][q], red[1][q]), fmaxf(red[2][q], red[3][q]));
    __syncthreads();
}

__device__ __forceinline__ void block_sum4(float* v, float (*red)[4])
{
    #pragma unroll
    for (int o = 32; o > 0; o >>= 1)
        #pragma unroll
        for (int q = 0; q < 4; ++q) v[q] += __shfl_down(v[q], o);
    const int lane = threadIdx.x & 63, w = threadIdx.x >> 6;
    if (lane == 0) { red[w][0]=v[0]; red[w][1]=v[1]; red[w][2]=v[2]; red[w][3]=v[3]; }
    __syncthreads();
    #pragma unroll
    for (int q = 0; q < 4; ++q)
        v[q] = red[0][q] + red[1][q] + red[2][q] + red[3][q];
    __syncthreads();
}

__global__ __launch_bounds__(256) void attn_kernel(
    const float* __restrict__ LR, const float* __restrict__ aW2,
    const float* __restrict__ ab2, const float* __restrict__ adj,
    __hip_bfloat16* __restrict__ att)
{
    __shared__ float sL[4][HH];
    __shared__ float sW[HH];
    __shared__ float red[4][4];

    const int b  = blockIdx.y;
    const int i0 = blockIdx.x * 4;
    const int j  = threadIdx.x;

    // prefetch adj + ab2 early: latency hides under the 256-iter score loop
    float a[4];
    #pragma unroll
    for (int q = 0; q < 4; ++q)
        a[q] = adj[((long long)(b * NN + i0 + q)) * NN + j];
    const float ab2v = ab2[0];

    sW[j] = aW2[j];
    #pragma unroll
    for (int q = 0; q < 4; ++q)
        sL[q][j] = LR[((long long)(b * NN + i0 + q)) * 512 + j];
    __syncthreads();

    const float* rp = LR + ((long long)(b * NN + j)) * 512 + HH;
    float acc[4] = {0.f, 0.f, 0.f, 0.f};
    for (int h = 0; h < HH; h += 8) {
        const float4 ra = *(const float4*)(rp + h);
        const float4 rb = *(const float4*)(rp + h + 4);
        const float4 w0 = *(const float4*)&sW[h];
        const float4 w1 = *(const float4*)&sW[h + 4];
        #pragma unroll
        for (int q = 0; q < 4; ++q) {
            const float4 l0 = *(const float4*)&sL[q][h];
            const float4 l1 = *(const float4*)&sL[q][h + 4];
            float s = fmaxf(l0.x + ra.x, 0.f) * w0.x;
            s += fmaxf(l0.y + ra.y, 0.f) * w0.y;
            s += fmaxf(l0.z + ra.z, 0.f) * w0.z;
            s += fmaxf(l0.w + ra.w, 0.f) * w0.w;
            s += fmaxf(l1.x + rb.x, 0.f) * w1.x;
            s += fmaxf(l1.y + rb.y, 0.f) * w1.y;
            s += fmaxf(l1.z + rb.z, 0.f) * w1.z;
            s += fmaxf(l1.w + rb.w, 0.f) * w1.w;
            acc[q] += s;
        }
    }

    float m[4];
    #pragma unroll
    for (int q = 0; q < 4; ++q) {
        float e = acc[q] + ab2v;
        e = (e > 0.f) ? e : 0.01f * e;                       // leaky_relu
        m[q] = (a[q] == 0.f) ? -1e9f : e;                    // mask
    }
    float mx[4] = {m[0], m[1], m[2], m[3]};
    block_max4(mx, red);
    float p[4];
    #pragma unroll
    for (int q = 0; q < 4; ++q) p[q] = __expf(m[q] - mx[q]);
    float s[4] = {p[0], p[1], p[2], p[3]};
    block_sum4(s, red);
    #pragma unroll
    for (int q = 0; q < 4; ++q)
        att[((long long)(b * NN + i0 + q)) * NN + j] = __float2bfloat16(p[q] / s[q] * a[q]);
}

// ---------------------------------------------------------------------------
// Launch
// ---------------------------------------------------------------------------
extern "C" void kernel_launch(void* const* d_in, const int* in_sizes, int n_in,
                              void* d_out, int out_size, void* d_ws, size_t ws_size,
                              hipStream_t stream)
{
    const float* feature = (const float*)d_in[0];
    const float* adj     = (const float*)d_in[1];
    const float* W0      = (const float*)d_in[2];
    const float* b0      = (const float*)d_in[3];
    const float* W1      = (const float*)d_in[4];
    const float* b1      = (const float*)d_in[5];
    const float* aW1     = (const float*)d_in[6];
    const float* ab1     = (const float*)d_in[7];
    const float* aW2     = (const float*)d_in[8];
    const float* ab2     = (const float*)d_in[9];
    float* out = (float*)d_out;

    __hip_bfloat16* bw = (__hip_bfloat16*)d_ws;
    __hip_bfloat16* xb   = bw;                       // 1024*640
    __hip_bfloat16* W0T  = xb   + MROWS * KPAD;      // 640*640
    __hip_bfloat16* W1T  = W0T  + KPAD * KPAD;       // 640*640
    __hip_bfloat16* aW1T = W1T  + KPAD * KPAD;       // 512*640
    __hip_bfloat16* hb   = aW1T + 512 * KPAD;        // 1024*640
    __hip_bfloat16* hT   = hb   + MROWS * KPAD;      // 4*640*256
    __hip_bfloat16* att  = hT   + BATCH * KPAD * NN; // 4*256*256
    float* LR = (float*)(att + BATCH * NN * NN);     // 1024*512 fp32

    prep_kernel<<<1760, 256, 0, stream>>>(feature, W0, W1, aW1, xb, W0T, W1T, aW1T);

    for (int layer = 0; layer < 2; ++layer) {
        const __hip_bfloat16* WT = layer ? W1T : W0T;
        const float* bb          = layer ? b1 : b0;

        // hb = x @ W + b  [1024][640] bf16 ; also hT[b][d][j]
        gemm_mfma<true, false, false, true, true, KPAD/64>
            <<<dim3(KPAD / 32, MROWS / 64, 1), 256, 0, stream>>>(
            xb, WT, bb, nullptr, hb, hT,
            KPAD, KPAD, 0, KPAD, 0, DD, 0, 0, 0, 0);

        // LR = hb @ aW1T^T (+ab1 on cols<256)   [1024][512] fp32
        gemm_mfma<true, false, true, false, false, KPAD/64>
            <<<dim3(512 / 32, MROWS / 64, 1), 256, 0, stream>>>(
            hb, aW1T, ab1, LR, nullptr, nullptr,
            KPAD, KPAD, 512, 0, 512, HH, 0, 0, 0, 0);

        // att = softmax(mask(leaky(score))) * adj   bf16
        attn_kernel<<<dim3(NN / 4, BATCH), 256, 0, stream>>>(LR, aW2, ab2, adj, att);

        // out = relu(att @ h): layer0 -> xb (bf16); layer1 -> out fp32
        if (layer == 0) {
            gemm_mfma<false, true, false, true, false, NN/64>
                <<<dim3(KPAD / 32, NN / 64, BATCH), 256, 0, stream>>>(
                att, hT, nullptr, nullptr, xb, nullptr,
                NN, NN, 0, KPAD, 0, 0,
                (long long)NN * NN, (long long)KPAD * NN, 0, (long long)NN * KPAD);
        } else {
            gemm_mfma<false, true, true, false, false, NN/64>
                <<<dim3(KPAD / 32, NN / 64, BATCH), 256, 0, stream>>>(
                att, hT, nullptr, out, nullptr, nullptr,
                NN, NN, DD, 0, DD, 0,
                (long long)NN * NN, (long long)KPAD * NN, (long long)NN * DD, 0);
        }
    }
}